// Round 5
// baseline (277.247 us; speedup 1.0000x reference)
//
#include <hip/hip_runtime.h>
#include <stdint.h>

typedef int v4i __attribute__((ext_vector_type(4)));

#define GLD_LDS16(gp, lp)                                                              \
  __builtin_amdgcn_global_load_lds((const __attribute__((address_space(1))) void*)(gp), \
                                   (__attribute__((address_space(3))) void*)(lp), 16, 0, 0)

__device__ __forceinline__ v4i lds_read_b128(uint32_t off) {
  v4i r;
  asm volatile("ds_read_b128 %0, %1" : "=v"(r) : "v"(off));
  return r;
}

// ---------------------------------------------------------------------------
__device__ __forceinline__ void fwht16(float v[16]) {
#pragma unroll
  for (int h = 1; h < 16; h <<= 1) {
#pragma unroll
    for (int i = 0; i < 16; ++i) {
      if (!(i & h)) {
        float a = v[i], b = v[i | h];
        v[i] = a + b;
        v[i | h] = a - b;
      }
    }
  }
}

__device__ __forceinline__ void fwht_row_load(const float* __restrict__ xr, int t,
                                              float v[16]) {
  const float4* p = reinterpret_cast<const float4*>(xr) + t * 4;
  float4 a = p[0], b = p[1], c = p[2], d = p[3];
  v[0] = a.x; v[1] = a.y; v[2] = a.z; v[3] = a.w;
  v[4] = b.x; v[5] = b.y; v[6] = b.z; v[7] = b.w;
  v[8] = c.x; v[9] = c.y; v[10] = c.z; v[11] = c.w;
  v[12] = d.x; v[13] = d.y; v[14] = d.z; v[15] = d.w;
}

// 3 register phases + 2 padded-LDS exchanges; bitwise-identical pair order to ref.
__device__ __forceinline__ void fwht4096(float v[16], float* lds, int t) {
  fwht16(v);
#pragma unroll
  for (int e = 0; e < 16; ++e) {
    int idx = t * 16 + e;
    lds[idx + (idx >> 5)] = v[e];
  }
  __syncthreads();
#pragma unroll
  for (int e = 0; e < 16; ++e) {
    int idx = ((t >> 4) << 8) + (e << 4) + (t & 15);
    v[e] = lds[idx + (idx >> 5)];
  }
  fwht16(v);
#pragma unroll
  for (int e = 0; e < 16; ++e) {
    int idx = ((t >> 4) << 8) + (e << 4) + (t & 15);
    lds[idx + (idx >> 5)] = v[e];
  }
  __syncthreads();
#pragma unroll
  for (int e = 0; e < 16; ++e) {
    int idx = (e << 8) + t;
    v[e] = lds[idx + (idx >> 5)];
  }
  fwht16(v);
#pragma unroll
  for (int e = 0; e < 16; ++e) v[e] *= 0.015625f;  // 1/sqrt(4096)
}

__global__ __launch_bounds__(256) void fwht_quant_kernel(const float* __restrict__ X,
                                                         int8_t* __restrict__ Q,
                                                         float* __restrict__ S) {
  const int row = blockIdx.x;
  const int t = threadIdx.x;
  __shared__ float lds[4224];
  __shared__ float wred[4];

  float v[16];
  fwht_row_load(X + (size_t)row * 4096, t, v);
  fwht4096(v, lds, t);

  float m = 0.f;
#pragma unroll
  for (int e = 0; e < 16; ++e) m = fmaxf(m, fabsf(v[e]));
#pragma unroll
  for (int off = 32; off > 0; off >>= 1) m = fmaxf(m, __shfl_xor(m, off));
  if ((t & 63) == 0) wred[t >> 6] = m;
  __syncthreads();
  m = fmaxf(fmaxf(wred[0], wred[1]), fmaxf(wred[2], wred[3]));
  const float s = fmaxf(m * (1.0f / 127.0f), 1e-8f);
  if (t == 0) S[row] = s;
  int8_t* qr = Q + (size_t)row * 4096;
#pragma unroll
  for (int e = 0; e < 16; ++e) {
    float q = rintf(v[e] / s);
    q = fminf(fmaxf(q, -127.f), 127.f);
    qr[(e << 8) + t] = (int8_t)(int)q;
  }
}

// FWHT without quantization (for lora_A -> Ah), fp32 out.
__global__ __launch_bounds__(256) void fwht_nq_kernel(const float* __restrict__ X,
                                                      float* __restrict__ F) {
  const int row = blockIdx.x;
  const int t = threadIdx.x;
  __shared__ float lds[4224];
  float v[16];
  fwht_row_load(X + (size_t)row * 4096, t, v);
  fwht4096(v, lds, t);
  float* fr = F + (size_t)row * 4096;
#pragma unroll
  for (int e = 0; e < 16; ++e) fr[(e << 8) + t] = v[e];
}

// ---------------------------------------------------------------------------
// t = dequant(qx) @ Ah^T  (exact identity: x@A^T == fwht(x)@fwht(A)^T).
// sx folded after the k-sum. Split-K over 8 chunks of 512, deterministic.
__global__ __launch_bounds__(256) void lora_t_partial_q(const int8_t* __restrict__ Qx,
                                                        const float* __restrict__ Sx,
                                                        const float* __restrict__ Ah,
                                                        float* __restrict__ tpart) {
  __shared__ float As[16][512];
  const int t = threadIdx.x;
  const int kc = blockIdx.y;
  const int row = blockIdx.x * 256 + t;
  for (int i = t; i < 2048; i += 256) {
    int r = i >> 7, c4 = i & 127;
    reinterpret_cast<float4*>(&As[r][0])[c4] =
        reinterpret_cast<const float4*>(Ah + (size_t)r * 4096 + kc * 512)[c4];
  }
  __syncthreads();
  float acc[16];
#pragma unroll
  for (int r = 0; r < 16; ++r) acc[r] = 0.f;
  const int8_t* xr = Qx + (size_t)row * 4096 + kc * 512;
  for (int k = 0; k < 512; k += 16) {
    int4 pv = *reinterpret_cast<const int4*>(xr + k);
    int us[4] = {pv.x, pv.y, pv.z, pv.w};
#pragma unroll
    for (int b = 0; b < 4; ++b) {
#pragma unroll
      for (int j = 0; j < 4; ++j) {
        float f = (float)((int)(int8_t)(us[b] >> (8 * j)));
        int kk = k + b * 4 + j;
#pragma unroll
        for (int r = 0; r < 16; ++r) acc[r] = fmaf(f, As[r][kk], acc[r]);
      }
    }
  }
  const float s = Sx[row];
  float* tp = tpart + ((size_t)kc * 8192 + row) * 16;
#pragma unroll
  for (int r = 0; r < 16; ++r) tp[r] = acc[r] * s;
}

__global__ __launch_bounds__(256) void lora_t_reduce_kernel(const float* __restrict__ tpart,
                                                            float* __restrict__ tmat) {
  int i = blockIdx.x * 256 + threadIdx.x;
  float s = 0.f;
#pragma unroll
  for (int kc = 0; kc < 8; ++kc) s += tpart[(size_t)kc * 131072 + i];
  tmat[i] = s;
}

// ---------------------------------------------------------------------------
// 256x256 i8 GEMM, 4-buffer ring, BK=64B, 64 K-steps, prefetch 3 ahead.
// LDS: 4 bufs x (A[256r][64B] + B[256r][64B]) = 128 KB.
// Swizzle: 16B chunk (0..3) ^= (row>>1)&3, both-sides.
// Per step: {issue stage(t+3) [4 gld_lds]; 12 ds_read; lgkm(4); 16 MFMA;
// lgkm(0); 16 MFMA; vmcnt(8); barrier}. vmcnt(8) leaves stages t+2,t+3 in
// flight across the barrier -- never drains (T4).
__global__ __launch_bounds__(512, 2) void gemm_i8_kernel(
    const int8_t* __restrict__ Aq, const int8_t* __restrict__ Bq,
    const float* __restrict__ Sx, const float* __restrict__ Sw,
    const float* __restrict__ Tm, const float* __restrict__ LB,
    float* __restrict__ out) {
  __shared__ __align__(16) char smem[131072];

  const int tid = threadIdx.x;
  const int lane = tid & 63;
  const int w = tid >> 6;      // 0..7
  const int wm = w >> 2;       // 0..1
  const int wn = w & 3;        // 0..3

  int bid = (int)blockIdx.x;
  bid = (bid & 7) * 64 + (bid >> 3);  // bijective XCD swizzle (512 % 8 == 0)
  const int bm = bid >> 4;            // 0..31
  const int bn = bid & 15;            // 0..15

  const int8_t* Ag = Aq + (size_t)bm * 256 * 4096;
  const int8_t* Bg = Bq + (size_t)bn * 256 * 4096;

  const uint32_t sbase = (uint32_t)(uintptr_t)(void*)smem;

  // ---- staging geometry: 2 loads per wave per operand per step ----
  // inst j covers rows w*32 + j*16 + (lane>>2), dest chunk lane&3 (linear LDS);
  // source chunk pre-swizzled: (lane&3) ^ ((row>>1)&3) = (lane&3) ^ ((lane>>3)&3).
  const size_t gA0 = (size_t)(w * 32 + (lane >> 2)) * 4096 +
                     (((lane & 3) ^ ((lane >> 3) & 3)) << 4);
  const size_t gA1 = gA0 + 16 * 4096;

#define STAGE_STEP(s)                                                   \
  do {                                                                  \
    char* dst = smem + ((s) & 3) * 32768 + w * 2048;                    \
    const size_t kb = (size_t)(s) << 6;                                 \
    GLD_LDS16(Ag + gA0 + kb, dst);                                      \
    GLD_LDS16(Ag + gA1 + kb, dst + 1024);                               \
    GLD_LDS16(Bg + gA0 + kb, dst + 16384);                              \
    GLD_LDS16(Bg + gA1 + kb, dst + 16384 + 1024);                       \
  } while (0)

  // ---- fragment LDS offsets (within a 32KB buffer) ----
  int aoff[8], boff[4];
#pragma unroll
  for (int mi = 0; mi < 8; ++mi) {
    int r = wm * 128 + mi * 16 + (lane & 15);
    aoff[mi] = r * 64 + ((((lane >> 4)) ^ ((r >> 1) & 3)) << 4);
  }
#pragma unroll
  for (int ni = 0; ni < 4; ++ni) {
    int r = wn * 64 + ni * 16 + (lane & 15);
    boff[ni] = 16384 + r * 64 + ((((lane >> 4)) ^ ((r >> 1) & 3)) << 4);
  }

  v4i acc[8][4];
#pragma unroll
  for (int i = 0; i < 8; ++i)
#pragma unroll
    for (int n = 0; n < 4; ++n) {
      v4i z = {0, 0, 0, 0};
      acc[i][n] = z;
    }

  // ---- prologue: stage steps 0,1,2 ----
  STAGE_STEP(0);
  STAGE_STEP(1);
  STAGE_STEP(2);
  asm volatile("s_waitcnt vmcnt(8)" ::: "memory");  // stage 0 landed
  __builtin_amdgcn_s_barrier();
  __builtin_amdgcn_sched_barrier(0);

#define MFMA16(MH)                                                                        \
  do {                                                                                    \
    __builtin_amdgcn_s_setprio(1);                                                        \
    _Pragma("unroll") for (int i = 0; i < 4; ++i) _Pragma("unroll") for (int n = 0;       \
                                                                        n < 4; ++n)       \
        acc[(MH)*4 + i][n] =                                                              \
        __builtin_amdgcn_mfma_i32_16x16x64_i8(af[i], bf[n], acc[(MH)*4 + i][n], 0, 0, 0); \
    __builtin_amdgcn_s_setprio(0);                                                        \
  } while (0)

#pragma unroll 1
  for (int t = 0; t < 64; ++t) {
    const uint32_t bufR = sbase + (t & 3) * 32768;
    if (t <= 60) STAGE_STEP(t + 3);

    v4i af[4], bf[4], af2[4];
#pragma unroll
    for (int n = 0; n < 4; ++n) bf[n] = lds_read_b128(bufR + boff[n]);
#pragma unroll
    for (int i = 0; i < 4; ++i) af[i] = lds_read_b128(bufR + aoff[i]);
#pragma unroll
    for (int i = 0; i < 4; ++i) af2[i] = lds_read_b128(bufR + aoff[4 + i]);
    asm volatile("s_waitcnt lgkmcnt(4)" ::: "memory");  // bf, af done; af2 flying
    __builtin_amdgcn_sched_barrier(0);
    MFMA16(0);
#pragma unroll
    for (int i = 0; i < 4; ++i) af[i] = af2[i];
    asm volatile("s_waitcnt lgkmcnt(0)" ::: "memory");
    __builtin_amdgcn_sched_barrier(0);
    MFMA16(1);

    // never drain: stage(t+1) landed, t+2/t+3 stay in flight
    if (t <= 60)
      asm volatile("s_waitcnt vmcnt(8)" ::: "memory");
    else if (t == 61)
      asm volatile("s_waitcnt vmcnt(4)" ::: "memory");
    else if (t == 62)
      asm volatile("s_waitcnt vmcnt(0)" ::: "memory");
    if (t < 63) {
      __builtin_amdgcn_s_barrier();
      __builtin_amdgcn_sched_barrier(0);
    }
  }

  // ---- epilogue: scales + fused LoRA ----
  __syncthreads();
  float* tl = (float*)smem;              // [256][17]
  float* bl = (float*)(smem + 17408);    // [256][17]
  for (int i = tid; i < 1024; i += 512) {
    int r = i >> 2, q4 = (i & 3) * 4;
    float4 tv = *reinterpret_cast<const float4*>(Tm + (size_t)(bm * 256 + r) * 16 + q4);
    tl[r * 17 + q4 + 0] = tv.x;
    tl[r * 17 + q4 + 1] = tv.y;
    tl[r * 17 + q4 + 2] = tv.z;
    tl[r * 17 + q4 + 3] = tv.w;
    float4 bv = *reinterpret_cast<const float4*>(LB + (size_t)(bn * 256 + r) * 16 + q4);
    bl[r * 17 + q4 + 0] = bv.x;
    bl[r * 17 + q4 + 1] = bv.y;
    bl[r * 17 + q4 + 2] = bv.z;
    bl[r * 17 + q4 + 3] = bv.w;
  }
  __syncthreads();

  float blv[4][16], swv[4];
#pragma unroll
  for (int ni = 0; ni < 4; ++ni) {
    int cl = wn * 64 + ni * 16 + (lane & 15);
    swv[ni] = Sw[bn * 256 + cl];
#pragma unroll
    for (int q = 0; q < 16; ++q) blv[ni][q] = bl[cl * 17 + q];
  }
#pragma unroll
  for (int mi = 0; mi < 8; ++mi) {
#pragma unroll
    for (int rr = 0; rr < 4; ++rr) {
      int rl = wm * 128 + mi * 16 + (lane >> 4) * 4 + rr;  // C/D: row=(l>>4)*4+reg
      float sxv = Sx[bm * 256 + rl];
      float tv[16];
#pragma unroll
      for (int q = 0; q < 16; ++q) tv[q] = tl[rl * 17 + q];
      float* orow = out + (size_t)(bm * 256 + rl) * 4096 + bn * 256;
#pragma unroll
      for (int ni = 0; ni < 4; ++ni) {
        float dot = 0.f;
#pragma unroll
        for (int q = 0; q < 16; ++q) dot = fmaf(tv[q], blv[ni][q], dot);
        int cl = wn * 64 + ni * 16 + (lane & 15);  // C/D: col = l&15
        orow[cl] = sxv * swv[ni] * (float)acc[mi][ni][rr] + 2.0f * dot;
      }
    }
  }
}

// ---------------------------------------------------------------------------
extern "C" void kernel_launch(void* const* d_in, const int* in_sizes, int n_in,
                              void* d_out, int out_size, void* d_ws, size_t ws_size,
                              hipStream_t stream) {
  const float* x = (const float*)d_in[0];     // 8192 x 4096
  const float* wgt = (const float*)d_in[1];   // 4096 x 4096
  const float* lA = (const float*)d_in[2];    // 16 x 4096
  const float* lB = (const float*)d_in[3];    // 4096 x 16
  float* out = (float*)d_out;                 // 8192 x 4096

  char* ws = (char*)d_ws;
  int8_t* qx = (int8_t*)ws;                    // 32 MB
  int8_t* qw = (int8_t*)(ws + 33554432);       // 16 MB
  float* sx = (float*)(ws + 50331648);         // 32 KB
  float* sw = (float*)(ws + 50364416);         // 16 KB
  float* tmat = (float*)(ws + 50380800);       // 512 KB
  float* tpart = (float*)(ws + 50905088);      // 4 MB
  float* Ah = (float*)(ws + 55099392);         // 256 KB

  fwht_quant_kernel<<<8192, 256, 0, stream>>>(x, qx, sx);
  fwht_quant_kernel<<<4096, 256, 0, stream>>>(wgt, qw, sw);
  fwht_nq_kernel<<<16, 256, 0, stream>>>(lA, Ah);
  lora_t_partial_q<<<dim3(32, 8), 256, 0, stream>>>(qx, sx, Ah, tpart);
  lora_t_reduce_kernel<<<512, 256, 0, stream>>>(tpart, tmat);
  gemm_i8_kernel<<<512, 512, 0, stream>>>(qx, qw, sx, sw, tmat, lB, out);
}